// Round 2
// baseline (5572.508 us; speedup 1.0000x reference)
//
#include <hip/hip_runtime.h>
#include <hip/hip_bf16.h>

#define DEVINL __device__ __forceinline__

constexpr int Bsz = 4096, INF = 1024, H1 = 2048, H2 = 2048, OUTD = 512, NE = 8, G = 256;

DEVINL float waveAllSum(float v) {
#pragma unroll
  for (int m = 32; m > 0; m >>= 1) v += __shfl_xor(v, m, 64);
  return v;
}

// ---------------- gate layer 1: g = relu(x @ Wg1 + bg1) ----------------
__global__ __launch_bounds__(256) void gate1_kernel(
    const float* __restrict__ x, const float* __restrict__ Wg1,
    const float* __restrict__ bg1, float* __restrict__ g) {
  __shared__ float xs[8 * 1024];
  const int b0 = blockIdx.x * 8;
  const float* xp = x + (size_t)b0 * INF;
  for (int idx = threadIdx.x * 4; idx < 8 * 1024; idx += 1024)
    *(float4*)&xs[idx] = *(const float4*)&xp[idx];
  __syncthreads();
  const int t = threadIdx.x;
  float acc[8] = {0, 0, 0, 0, 0, 0, 0, 0};
  for (int i = 0; i < INF; ++i) {
    float w = Wg1[(size_t)i * G + t];
#pragma unroll
    for (int r = 0; r < 8; ++r) acc[r] = fmaf(xs[r * 1024 + i], w, acc[r]);
  }
  const float bb = bg1[t];
#pragma unroll
  for (int r = 0; r < 8; ++r)
    g[(size_t)(b0 + r) * G + t] = fmaxf(acc[r] + bb, 0.0f);
}

// ---------------- gate layer 2 + softmax ----------------
__global__ __launch_bounds__(64) void gate2_kernel(
    const float* __restrict__ g, const float* __restrict__ Wg2,
    const float* __restrict__ bg2, float* __restrict__ gw) {
  const int b = blockIdx.x, lane = threadIdx.x;
  float4 gv = *(const float4*)(g + (size_t)b * G + lane * 4);
  float p[8];
#pragma unroll
  for (int e = 0; e < 8; ++e) {
    int j = lane * 4;
    float s = gv.x * Wg2[(j + 0) * 8 + e] + gv.y * Wg2[(j + 1) * 8 + e] +
              gv.z * Wg2[(j + 2) * 8 + e] + gv.w * Wg2[(j + 3) * 8 + e];
    p[e] = waveAllSum(s);
  }
  if (lane == 0) {
    float l[8];
    float mx = -1e30f;
#pragma unroll
    for (int e = 0; e < 8; ++e) {
      l[e] = p[e] + bg2[e];
      mx = fmaxf(mx, l[e]);
    }
    float sum = 0.0f;
#pragma unroll
    for (int e = 0; e < 8; ++e) {
      l[e] = expf(l[e] - mx);
      sum += l[e];
    }
    float inv = 1.0f / sum;
#pragma unroll
    for (int e = 0; e < 8; ++e) gw[(size_t)b * 8 + e] = l[e] * inv;
  }
}

// ---------------- f32 tiled GEMM, per-expert (grid.z = e) ----------------
// C[e][M][N] = act(A[e][M][K] @ Bw[e][K][N] + bias[e][N]); 128x128 tile, BK=8.
template <int RELU>
__global__ __launch_bounds__(256) void gemm_f32_kernel(
    const float* __restrict__ A, const float* __restrict__ Bw,
    const float* __restrict__ bias, float* __restrict__ C,
    int M, int N, int K, size_t strideAe) {
  const int e = blockIdx.z;
  A += (size_t)e * strideAe;
  Bw += (size_t)e * K * N;
  bias += (size_t)e * N;
  C += (size_t)e * (size_t)M * N;
  const int bm = blockIdx.y * 128, bn = blockIdx.x * 128;
  __shared__ float As[8][132];
  __shared__ float Bs[8][132];
  const int tid = threadIdx.x;
  const int tx = tid & 15, ty = tid >> 4;
  const int ar = tid >> 1, ak = (tid & 1) * 4;
  const int bk = tid >> 5, bn4 = (tid & 31) * 4;
  const float* Ap = A + (size_t)(bm + ar) * K + ak;
  const float* Bp = Bw + (size_t)bk * N + bn + bn4;
  float4 av = *(const float4*)Ap;
  float4 bv = *(const float4*)Bp;
  float acc[8][8];
#pragma unroll
  for (int i = 0; i < 8; ++i)
#pragma unroll
    for (int j = 0; j < 8; ++j) acc[i][j] = 0.0f;

  for (int k0 = 0; k0 < K; k0 += 8) {
    __syncthreads();
    As[ak + 0][ar] = av.x;
    As[ak + 1][ar] = av.y;
    As[ak + 2][ar] = av.z;
    As[ak + 3][ar] = av.w;
    *(float4*)&Bs[bk][bn4] = bv;
    __syncthreads();
    if (k0 + 8 < K) {
      av = *(const float4*)(Ap + k0 + 8);
      bv = *(const float4*)(Bp + (size_t)(k0 + 8) * N);
    }
#pragma unroll
    for (int kk = 0; kk < 8; ++kk) {
      float4 a0 = *(const float4*)&As[kk][ty * 8];
      float4 a1 = *(const float4*)&As[kk][ty * 8 + 4];
      float4 b0 = *(const float4*)&Bs[kk][tx * 8];
      float4 b1 = *(const float4*)&Bs[kk][tx * 8 + 4];
      float am[8] = {a0.x, a0.y, a0.z, a0.w, a1.x, a1.y, a1.z, a1.w};
      float bw[8] = {b0.x, b0.y, b0.z, b0.w, b1.x, b1.y, b1.z, b1.w};
#pragma unroll
      for (int i = 0; i < 8; ++i)
#pragma unroll
        for (int j = 0; j < 8; ++j) acc[i][j] = fmaf(am[i], bw[j], acc[i][j]);
    }
  }
  float bb[8];
#pragma unroll
  for (int j = 0; j < 8; ++j) bb[j] = bias[bn + tx * 8 + j];
#pragma unroll
  for (int i = 0; i < 8; ++i) {
    const int row = bm + ty * 8 + i;
    float o[8];
#pragma unroll
    for (int j = 0; j < 8; ++j) {
      float v = acc[i][j] + bb[j];
      if (RELU) v = fmaxf(v, 0.0f);
      o[j] = v;
    }
    *(float4*)&C[(size_t)row * N + bn + tx * 8] = make_float4(o[0], o[1], o[2], o[3]);
    *(float4*)&C[(size_t)row * N + bn + tx * 8 + 4] = make_float4(o[4], o[5], o[6], o[7]);
  }
}

// ---------------- Gram-Schmidt + gated combine + output projection ----------------
// eo layout [E][CB][OUT]; gw/out pointers pre-offset to this chunk.
__global__ __launch_bounds__(256) void gs_kernel(
    const float* __restrict__ eo, const float* __restrict__ gw,
    const float* __restrict__ Wo, const float* __restrict__ bo,
    float* __restrict__ out, int CB) {
  const int lane = threadIdx.x & 63;
  const int b = blockIdx.x * 4 + (threadIdx.x >> 6);
  const size_t ES = (size_t)CB * OUTD;
  const float* base = eo + (size_t)b * OUTD + lane * 8;
  float vs[8][8];
  float denom[8];
#pragma unroll
  for (int i = 0; i < 8; ++i) {
    float cur[8];
    float4 u0 = *(const float4*)(base + (size_t)i * ES);
    float4 u1 = *(const float4*)(base + (size_t)i * ES + 4);
    cur[0] = u0.x; cur[1] = u0.y; cur[2] = u0.z; cur[3] = u0.w;
    cur[4] = u1.x; cur[5] = u1.y; cur[6] = u1.z; cur[7] = u1.w;
#pragma unroll
    for (int j = 0; j < i; ++j) {
      float dp = 0.0f;
#pragma unroll
      for (int d = 0; d < 8; ++d) dp = fmaf(cur[d], vs[j][d], dp);
      dp = waveAllSum(dp);
      float coeff = dp / (denom[j] + 1e-6f);
#pragma unroll
      for (int d = 0; d < 8; ++d) cur[d] = fmaf(-coeff, vs[j][d], cur[d]);
    }
    float nn = 0.0f;
#pragma unroll
    for (int d = 0; d < 8; ++d) nn = fmaf(cur[d], cur[d], nn);
    nn = waveAllSum(nn);
    float inv = 1.0f / fmaxf(sqrtf(nn), 1e-6f);
#pragma unroll
    for (int d = 0; d < 8; ++d) vs[i][d] = cur[d] * inv;
    float dd = 0.0f;
#pragma unroll
    for (int d = 0; d < 8; ++d) dd = fmaf(vs[i][d], vs[i][d], dd);
    denom[i] = waveAllSum(dd);
  }
  float gwv[8];
#pragma unroll
  for (int e = 0; e < 8; ++e) gwv[e] = gw[(size_t)b * 8 + e];
  float part = 0.0f;
#pragma unroll
  for (int d = 0; d < 8; ++d) {
    float c = 0.0f;
#pragma unroll
    for (int e = 0; e < 8; ++e) c = fmaf(vs[e][d], gwv[e], c);
    part = fmaf(c, Wo[lane * 8 + d], part);
  }
  part = waveAllSum(part);
  if (lane == 0) out[b] = part + bo[0];
}

extern "C" void kernel_launch(void* const* d_in, const int* in_sizes, int n_in,
                              void* d_out, int out_size, void* d_ws, size_t ws_size,
                              hipStream_t stream) {
  const float* x   = (const float*)d_in[0];
  const float* W1  = (const float*)d_in[1];
  const float* b1  = (const float*)d_in[2];
  const float* W2  = (const float*)d_in[3];
  const float* b2  = (const float*)d_in[4];
  const float* W3  = (const float*)d_in[5];
  const float* b3  = (const float*)d_in[6];
  const float* Wg1 = (const float*)d_in[7];
  const float* bg1 = (const float*)d_in[8];
  const float* Wg2 = (const float*)d_in[9];
  const float* bg2 = (const float*)d_in[10];
  const float* Wo  = (const float*)d_in[11];
  const float* bo  = (const float*)d_in[12];
  float* out = (float*)d_out;

  char* ws = (char*)d_ws;
  // layout: [gw 128KB][g 4MB] ... chunk region at 8MB
  float* gw = (float*)(ws);
  float* g  = (float*)(ws + (size_t)(128u << 10));
  const size_t baseOff = (size_t)(8u << 20);

  // pick largest batch-chunk CB (multiple of 128) whose h1+h2 fits ws:
  // per-chunk bytes = CB * (8*2048*4 * 2) = CB * 128KB
  int CB = 4096;
  while (CB > 128 && baseOff + (size_t)CB * (size_t)(128u << 10) > ws_size) CB >>= 1;

  hipMemsetAsync(d_out, 0, (size_t)out_size * sizeof(float), stream);

  gate1_kernel<<<Bsz / 8, 256, 0, stream>>>(x, Wg1, bg1, g);
  gate2_kernel<<<Bsz, 64, 0, stream>>>(g, Wg2, bg2, gw);

  float* h1c = (float*)(ws + baseOff);
  float* h2c = (float*)(ws + baseOff + (size_t)CB * (size_t)NE * H1 * sizeof(float));

  for (int c0 = 0; c0 < Bsz; c0 += CB) {
    gemm_f32_kernel<1><<<dim3(H1 / 128, CB / 128, NE), 256, 0, stream>>>(
        x + (size_t)c0 * INF, W1, b1, h1c, CB, H1, INF, (size_t)0);
    gemm_f32_kernel<1><<<dim3(H2 / 128, CB / 128, NE), 256, 0, stream>>>(
        h1c, W2, b2, h2c, CB, H2, H1, (size_t)CB * H1);
    gemm_f32_kernel<0><<<dim3(OUTD / 128, CB / 128, NE), 256, 0, stream>>>(
        h2c, W3, b3, h1c /*eo reuses h1*/, CB, OUTD, H2, (size_t)CB * H2);
    gs_kernel<<<CB / 4, 256, 0, stream>>>(h1c, gw + (size_t)c0 * NE, Wo, bo,
                                          out + c0, CB);
  }
}

// Round 3
// 2212.499 us; speedup vs baseline: 2.5186x; 2.5186x over previous
//
#include <hip/hip_runtime.h>
#include <hip/hip_bf16.h>

#define DEVINL __device__ __forceinline__

constexpr int Bsz = 4096, INF = 1024, H1 = 2048, H2 = 2048, OUTD = 512, NE = 8, G = 256;

typedef __attribute__((ext_vector_type(8))) short bf16x8;
typedef __attribute__((ext_vector_type(4))) float f32x4;

DEVINL unsigned short f2bf(float f) {  // RNE f32 -> bf16 bits
  unsigned int u = __float_as_uint(f);
  u = (u + 0x7FFFu + ((u >> 16) & 1u)) >> 16;
  return (unsigned short)u;
}
DEVINL float bf2f(unsigned short h) { return __uint_as_float((unsigned int)h << 16); }

DEVINL void gload16(const void* g, void* l) {
  __builtin_amdgcn_global_load_lds(
      (const __attribute__((address_space(1))) void*)g,
      (__attribute__((address_space(3))) void*)l, 16, 0, 0);
}

DEVINL float waveAllSum(float v) {
#pragma unroll
  for (int m = 32; m > 0; m >>= 1) v += __shfl_xor(v, m, 64);
  return v;
}

// ---------------- pack x -> hi/lo bf16 (row-major) ----------------
__global__ __launch_bounds__(256) void pack_act(const float* __restrict__ in,
                                                unsigned short* __restrict__ hi,
                                                unsigned short* __restrict__ lo) {
  size_t i = ((size_t)blockIdx.x * 256 + threadIdx.x) * 4;
  float4 v = *(const float4*)&in[i];
  short4 h, l;
  h.x = f2bf(v.x); l.x = f2bf(v.x - bf2f(h.x));
  h.y = f2bf(v.y); l.y = f2bf(v.y - bf2f(h.y));
  h.z = f2bf(v.z); l.z = f2bf(v.z - bf2f(h.z));
  h.w = f2bf(v.w); l.w = f2bf(v.w - bf2f(h.w));
  *(short4*)&hi[i] = h;
  *(short4*)&lo[i] = l;
}

// ---------------- pack W[e][K][N] f32 -> Wt hi/lo bf16 [e][N][K] ----------------
__global__ __launch_bounds__(256) void pack_wt(const float* __restrict__ W,
                                               unsigned short* __restrict__ Th,
                                               unsigned short* __restrict__ Tl,
                                               int K, int N) {
  __shared__ float t[32][33];
  const int e = blockIdx.z;
  W += (size_t)e * K * N;
  Th += (size_t)e * N * K;
  Tl += (size_t)e * N * K;
  const int n0 = blockIdx.x * 32, k0 = blockIdx.y * 32;
  const int r = threadIdx.x >> 3, c = (threadIdx.x & 7) * 4;
  float4 v = *(const float4*)&W[(size_t)(k0 + r) * N + n0 + c];
  t[r][c + 0] = v.x; t[r][c + 1] = v.y; t[r][c + 2] = v.z; t[r][c + 3] = v.w;
  __syncthreads();
  float o0 = t[c + 0][r], o1 = t[c + 1][r], o2 = t[c + 2][r], o3 = t[c + 3][r];
  short4 h, l;
  h.x = f2bf(o0); l.x = f2bf(o0 - bf2f(h.x));
  h.y = f2bf(o1); l.y = f2bf(o1 - bf2f(h.y));
  h.z = f2bf(o2); l.z = f2bf(o2 - bf2f(h.z));
  h.w = f2bf(o3); l.w = f2bf(o3 - bf2f(h.w));
  *(short4*)&Th[(size_t)(n0 + r) * K + k0 + c] = h;
  *(short4*)&Tl[(size_t)(n0 + r) * K + k0 + c] = l;
}

// ---------------- bf16x3 MFMA GEMM ----------------
// C[e][M][N] = act(A[e] @ B[e]^T + bias[e]); A hi/lo row-major [M][K],
// Bt hi/lo [N][K]. 128x128 tile, BK=32, 4 waves, 16x16x32 bf16 MFMA.
// LDS: 4 parts x 8 frags x 1KB (fragment-packed, lane-linear).
// MFMA called swapped (b,a,acc) => lane holds 4 consecutive C-cols.
template <int RELU, int OUTF32>
__global__ __launch_bounds__(256) void gemm_bf16x3(
    const unsigned short* __restrict__ Ahi, const unsigned short* __restrict__ Alo,
    const unsigned short* __restrict__ Bhi, const unsigned short* __restrict__ Blo,
    const float* __restrict__ bias,
    unsigned short* __restrict__ Chi, unsigned short* __restrict__ Clo,
    float* __restrict__ Cf, int M, int N, int K, size_t strideAe) {
  const int e = blockIdx.z;
  Ahi += (size_t)e * strideAe;
  Alo += (size_t)e * strideAe;
  Bhi += (size_t)e * (size_t)N * K;
  Blo += (size_t)e * (size_t)N * K;
  bias += (size_t)e * N;
  if (OUTF32) Cf += (size_t)e * (size_t)M * N;
  else { Chi += (size_t)e * (size_t)M * N; Clo += (size_t)e * (size_t)M * N; }

  const int bm = blockIdx.y * 128, bn = blockIdx.x * 128;
  __shared__ unsigned short lds[16384];  // 32KB
  char* ldsb = (char*)lds;
  const int lane = threadIdx.x & 63, wid = threadIdx.x >> 6;
  const int wr = wid >> 1, wc = wid & 1;
  const int l15 = lane & 15, l4 = lane >> 4;

  // staging role: wave 0->Ahi, 1->Alo, 2->Bhi, 3->Blo (8 frags each)
  const unsigned short* sb;
  int t0;
  if (wid == 0)      { sb = Ahi; t0 = bm; }
  else if (wid == 1) { sb = Alo; t0 = bm; }
  else if (wid == 2) { sb = Bhi; t0 = bn; }
  else               { sb = Blo; t0 = bn; }
  const unsigned short* gp0 = sb + (size_t)(t0 + l15) * K + l4 * 8;
  char* ldsw = ldsb + wid * 8192;

  f32x4 acc[4][4];
#pragma unroll
  for (int i = 0; i < 4; ++i)
#pragma unroll
    for (int j = 0; j < 4; ++j) acc[i][j] = (f32x4){0.f, 0.f, 0.f, 0.f};

  for (int k0 = 0; k0 < K; k0 += 32) {
    __syncthreads();
#pragma unroll
    for (int f = 0; f < 8; ++f)
      gload16(gp0 + (size_t)(f * 16) * K + k0, ldsw + f * 1024);
    __syncthreads();
    bf16x8 ah[4], al[4], bh[4], bl[4];
#pragma unroll
    for (int i = 0; i < 4; ++i) {
      ah[i] = *(const bf16x8*)(ldsb + 0     + (wr * 4 + i) * 1024 + lane * 16);
      al[i] = *(const bf16x8*)(ldsb + 8192  + (wr * 4 + i) * 1024 + lane * 16);
      bh[i] = *(const bf16x8*)(ldsb + 16384 + (wc * 4 + i) * 1024 + lane * 16);
      bl[i] = *(const bf16x8*)(ldsb + 24576 + (wc * 4 + i) * 1024 + lane * 16);
    }
#pragma unroll
    for (int i = 0; i < 4; ++i)
#pragma unroll
      for (int j = 0; j < 4; ++j) {
        acc[i][j] = __builtin_amdgcn_mfma_f32_16x16x32_bf16(bh[j], ah[i], acc[i][j], 0, 0, 0);
        acc[i][j] = __builtin_amdgcn_mfma_f32_16x16x32_bf16(bl[j], ah[i], acc[i][j], 0, 0, 0);
        acc[i][j] = __builtin_amdgcn_mfma_f32_16x16x32_bf16(bh[j], al[i], acc[i][j], 0, 0, 0);
      }
  }

  // epilogue: lane holds C[row=bm+wr*64+i*16+l15][col=bn+wc*64+j*16+l4*4+q]
#pragma unroll
  for (int i = 0; i < 4; ++i) {
    const int grow = bm + wr * 64 + i * 16 + l15;
#pragma unroll
    for (int j = 0; j < 4; ++j) {
      const int gcol = bn + wc * 64 + j * 16 + l4 * 4;
      const float4 bb = *(const float4*)&bias[gcol];
      float v0 = acc[i][j][0] + bb.x, v1 = acc[i][j][1] + bb.y;
      float v2 = acc[i][j][2] + bb.z, v3 = acc[i][j][3] + bb.w;
      if (RELU) {
        v0 = fmaxf(v0, 0.f); v1 = fmaxf(v1, 0.f);
        v2 = fmaxf(v2, 0.f); v3 = fmaxf(v3, 0.f);
      }
      if (OUTF32) {
        *(float4*)&Cf[(size_t)grow * N + gcol] = make_float4(v0, v1, v2, v3);
      } else {
        short4 h, l;
        h.x = f2bf(v0); l.x = f2bf(v0 - bf2f(h.x));
        h.y = f2bf(v1); l.y = f2bf(v1 - bf2f(h.y));
        h.z = f2bf(v2); l.z = f2bf(v2 - bf2f(h.z));
        h.w = f2bf(v3); l.w = f2bf(v3 - bf2f(h.w));
        *(short4*)&Chi[(size_t)grow * N + gcol] = h;
        *(short4*)&Clo[(size_t)grow * N + gcol] = l;
      }
    }
  }
}

// ---------------- gate layer 1 ----------------
__global__ __launch_bounds__(256) void gate1_kernel(
    const float* __restrict__ x, const float* __restrict__ Wg1,
    const float* __restrict__ bg1, float* __restrict__ g) {
  __shared__ float xs[8 * 1024];
  const int b0 = blockIdx.x * 8;
  const float* xp = x + (size_t)b0 * INF;
  for (int idx = threadIdx.x * 4; idx < 8 * 1024; idx += 1024)
    *(float4*)&xs[idx] = *(const float4*)&xp[idx];
  __syncthreads();
  const int t = threadIdx.x;
  float acc[8] = {0, 0, 0, 0, 0, 0, 0, 0};
  for (int i = 0; i < INF; ++i) {
    float w = Wg1[(size_t)i * G + t];
#pragma unroll
    for (int r = 0; r < 8; ++r) acc[r] = fmaf(xs[r * 1024 + i], w, acc[r]);
  }
  const float bb = bg1[t];
#pragma unroll
  for (int r = 0; r < 8; ++r)
    g[(size_t)(b0 + r) * G + t] = fmaxf(acc[r] + bb, 0.0f);
}

// ---------------- gate layer 2 + softmax ----------------
__global__ __launch_bounds__(64) void gate2_kernel(
    const float* __restrict__ g, const float* __restrict__ Wg2,
    const float* __restrict__ bg2, float* __restrict__ gw) {
  const int b = blockIdx.x, lane = threadIdx.x;
  float4 gv = *(const float4*)(g + (size_t)b * G + lane * 4);
  float p[8];
#pragma unroll
  for (int e = 0; e < 8; ++e) {
    int j = lane * 4;
    float s = gv.x * Wg2[(j + 0) * 8 + e] + gv.y * Wg2[(j + 1) * 8 + e] +
              gv.z * Wg2[(j + 2) * 8 + e] + gv.w * Wg2[(j + 3) * 8 + e];
    p[e] = waveAllSum(s);
  }
  if (lane == 0) {
    float l[8];
    float mx = -1e30f;
#pragma unroll
    for (int e = 0; e < 8; ++e) {
      l[e] = p[e] + bg2[e];
      mx = fmaxf(mx, l[e]);
    }
    float sum = 0.0f;
#pragma unroll
    for (int e = 0; e < 8; ++e) {
      l[e] = expf(l[e] - mx);
      sum += l[e];
    }
    float inv = 1.0f / sum;
#pragma unroll
    for (int e = 0; e < 8; ++e) gw[(size_t)b * 8 + e] = l[e] * inv;
  }
}

// ---------------- Gram-Schmidt + combine + out-proj ----------------
__global__ __launch_bounds__(256) void gs_kernel(
    const float* __restrict__ eo, const float* __restrict__ gw,
    const float* __restrict__ Wo, const float* __restrict__ bo,
    float* __restrict__ out, int CB) {
  const int lane = threadIdx.x & 63;
  const int b = blockIdx.x * 4 + (threadIdx.x >> 6);
  const size_t ES = (size_t)CB * OUTD;
  const float* base = eo + (size_t)b * OUTD + lane * 8;
  float vs[8][8];
  float denom[8];
#pragma unroll
  for (int i = 0; i < 8; ++i) {
    float cur[8];
    float4 u0 = *(const float4*)(base + (size_t)i * ES);
    float4 u1 = *(const float4*)(base + (size_t)i * ES + 4);
    cur[0] = u0.x; cur[1] = u0.y; cur[2] = u0.z; cur[3] = u0.w;
    cur[4] = u1.x; cur[5] = u1.y; cur[6] = u1.z; cur[7] = u1.w;
#pragma unroll
    for (int j = 0; j < i; ++j) {
      float dp = 0.0f;
#pragma unroll
      for (int d = 0; d < 8; ++d) dp = fmaf(cur[d], vs[j][d], dp);
      dp = waveAllSum(dp);
      float coeff = dp / (denom[j] + 1e-6f);
#pragma unroll
      for (int d = 0; d < 8; ++d) cur[d] = fmaf(-coeff, vs[j][d], cur[d]);
    }
    float nn = 0.0f;
#pragma unroll
    for (int d = 0; d < 8; ++d) nn = fmaf(cur[d], cur[d], nn);
    nn = waveAllSum(nn);
    float inv = 1.0f / fmaxf(sqrtf(nn), 1e-6f);
#pragma unroll
    for (int d = 0; d < 8; ++d) vs[i][d] = cur[d] * inv;
    float dd = 0.0f;
#pragma unroll
    for (int d = 0; d < 8; ++d) dd = fmaf(vs[i][d], vs[i][d], dd);
    denom[i] = waveAllSum(dd);
  }
  float gwv[8];
#pragma unroll
  for (int e = 0; e < 8; ++e) gwv[e] = gw[(size_t)b * 8 + e];
  float part = 0.0f;
#pragma unroll
  for (int d = 0; d < 8; ++d) {
    float c = 0.0f;
#pragma unroll
    for (int e = 0; e < 8; ++e) c = fmaf(vs[e][d], gwv[e], c);
    part = fmaf(c, Wo[lane * 8 + d], part);
  }
  part = waveAllSum(part);
  if (lane == 0) out[b] = part + bo[0];
}

extern "C" void kernel_launch(void* const* d_in, const int* in_sizes, int n_in,
                              void* d_out, int out_size, void* d_ws, size_t ws_size,
                              hipStream_t stream) {
  const float* x   = (const float*)d_in[0];
  const float* W1  = (const float*)d_in[1];
  const float* b1  = (const float*)d_in[2];
  const float* W2  = (const float*)d_in[3];
  const float* b2  = (const float*)d_in[4];
  const float* W3  = (const float*)d_in[5];
  const float* b3  = (const float*)d_in[6];
  const float* Wg1 = (const float*)d_in[7];
  const float* bg1 = (const float*)d_in[8];
  const float* Wg2 = (const float*)d_in[9];
  const float* bg2 = (const float*)d_in[10];
  const float* Wo  = (const float*)d_in[11];
  const float* bo  = (const float*)d_in[12];
  float* out = (float*)d_out;

  typedef unsigned short u16;
  char* p = (char*)d_ws;
  float* gw = (float*)p;          p += (size_t)(128u << 10);
  float* g  = (float*)p;          p += (size_t)(4u << 20);
  u16* xhi = (u16*)p;             p += (size_t)Bsz * INF * 2;
  u16* xlo = (u16*)p;             p += (size_t)Bsz * INF * 2;
  u16* w1h = (u16*)p;             p += (size_t)NE * H1 * INF * 2;
  u16* w1l = (u16*)p;             p += (size_t)NE * H1 * INF * 2;
  u16* w2h = (u16*)p;             p += (size_t)NE * H2 * H1 * 2;
  u16* w2l = (u16*)p;             p += (size_t)NE * H2 * H1 * 2;
  u16* w3h = (u16*)p;             p += (size_t)NE * OUTD * H2 * 2;
  u16* w3l = (u16*)p;             p += (size_t)NE * OUTD * H2 * 2;
  const size_t fixedBytes = (size_t)(p - (char*)d_ws);

  // chunk region: h1 hi/lo (CB*32KB each) + h2 hi/lo (CB*32KB each) = CB*128KB
  int CB = 4096;
  while (CB > 128 && fixedBytes + (size_t)CB * (size_t)(128u << 10) > ws_size) CB >>= 1;
  u16* h1h = (u16*)p;
  u16* h1l = h1h + (size_t)NE * CB * H1;
  u16* h2h = h1l + (size_t)NE * CB * H1;
  u16* h2l = h2h + (size_t)NE * CB * H2;
  float* eo = (float*)h1h;  // layer-3 f32 out reuses h1 region (dead by then)

  hipMemsetAsync(d_out, 0, (size_t)out_size * sizeof(float), stream);

  // pack inputs/weights (once)
  pack_act<<<(Bsz * INF) / 1024, 256, 0, stream>>>(x, xhi, xlo);
  pack_wt<<<dim3(H1 / 32, INF / 32, NE), 256, 0, stream>>>(W1, w1h, w1l, INF, H1);
  pack_wt<<<dim3(H2 / 32, H1 / 32, NE), 256, 0, stream>>>(W2, w2h, w2l, H1, H2);
  pack_wt<<<dim3(OUTD / 32, H2 / 32, NE), 256, 0, stream>>>(W3, w3h, w3l, H2, OUTD);

  gate1_kernel<<<Bsz / 8, 256, 0, stream>>>(x, Wg1, bg1, g);
  gate2_kernel<<<Bsz, 64, 0, stream>>>(g, Wg2, bg2, gw);

  for (int c0 = 0; c0 < Bsz; c0 += CB) {
    gemm_bf16x3<1, 0><<<dim3(H1 / 128, CB / 128, NE), 256, 0, stream>>>(
        xhi + (size_t)c0 * INF, xlo + (size_t)c0 * INF, w1h, w1l, b1,
        h1h, h1l, nullptr, CB, H1, INF, (size_t)0);
    gemm_bf16x3<1, 0><<<dim3(H2 / 128, CB / 128, NE), 256, 0, stream>>>(
        h1h, h1l, w2h, w2l, b2, h2h, h2l, nullptr, CB, H2, H1, (size_t)CB * H1);
    gemm_bf16x3<0, 1><<<dim3(OUTD / 128, CB / 128, NE), 256, 0, stream>>>(
        h2h, h2l, w3h, w3l, b3, nullptr, nullptr, eo, CB, OUTD, H2, (size_t)CB * H2);
    gs_kernel<<<CB / 4, 256, 0, stream>>>(eo, gw + (size_t)c0 * NE, Wo, bo,
                                          out + c0, CB);
  }
}